// Round 2
// baseline (376.676 us; speedup 1.0000x reference)
//
#include <hip/hip_runtime.h>

// Problem constants (match reference)
#define BB 8
#define NN 65536
#define DD 192
#define EPSV 1e-5f

#define CAX 24                       // coarse cells per axis (192/8, cell = 8^3 voxels)
#define CELLS_B (CAX * CAX * CAX)    // 13824 cells per batch
#define TCELLS (BB * CELLS_B)        // 110592 total cells
#define NPTS (BB * NN)               // 524288 points
#define SCAN_BLOCKS (TCELLS / 256)   // 432 (exact)

// d_out layout: dss [B*N] | nss [B*N*3] | loss [1]
// d_ws layout (u32 units):
//   [0, TCELLS)                    hist / cursor
//   [TCELLS, TCELLS+512)           block sums for scan
//   SORT0 + 0*NPTS  s_fx (f32)
//   SORT0 + 1*NPTS  s_fy (f32)
//   SORT0 + 2*NPTS  s_fz (f32)
//   SORT0 + 3*NPTS  s_base (u32: b<<24 | bx<<16 | by<<8 | bz)
//   SORT0 + 4*NPTS  s_orig (u32)
#define SORT0 (TCELLS + 512)

__device__ __forceinline__ void point_setup(
    const float* __restrict__ pss, const float* __restrict__ first,
    const float* __restrict__ coef, const float* __restrict__ maxl,
    int t, int& b, float& fx, float& fy, float& fz,
    int& bx, int& by, int& bz, int& key)
{
    b = t >> 16;                      // N == 65536
    const int n = t & (NN - 1);
    const float* pb = pss + (size_t)b * 3 * NN + n;
    const float px = pb[0];
    const float py = pb[NN];
    const float pz = pb[2 * NN];

    const float Fx = fmaxf(fminf((px - first[3*b+0]) * coef[3*b+0], maxl[3*b+0]), 0.0f);
    const float Fy = fmaxf(fminf((py - first[3*b+1]) * coef[3*b+1], maxl[3*b+1]), 0.0f);
    const float Fz = fmaxf(fminf((pz - first[3*b+2]) * coef[3*b+2], maxl[3*b+2]), 0.0f);

    bx = (int)floorf(Fx);
    by = (int)floorf(Fy);
    bz = (int)floorf(Fz);
    fx = Fx - (float)bx;
    fy = Fy - (float)by;
    fz = Fz - (float)bz;

    key = ((b * CAX + (bx >> 3)) * CAX + (by >> 3)) * CAX + (bz >> 3);
}

// ---------------- Pass A: per-cell histogram ----------------
__global__ __launch_bounds__(256) void hist_kernel(
    const float* __restrict__ pss, const float* __restrict__ first,
    const float* __restrict__ coef, const float* __restrict__ maxl,
    unsigned* __restrict__ hist)
{
    const int t = blockIdx.x * blockDim.x + threadIdx.x;
    int b, bx, by, bz, key; float fx, fy, fz;
    point_setup(pss, first, coef, maxl, t, b, fx, fy, fz, bx, by, bz, key);
    atomicAdd(&hist[key], 1u);
}

// ---------------- Pass B: 3-kernel exclusive scan over TCELLS ----------------
__global__ __launch_bounds__(256) void scan1_kernel(unsigned* __restrict__ hist,
                                                    unsigned* __restrict__ bsum)
{
    __shared__ unsigned s[256];
    const int tid = threadIdx.x;
    const int i = blockIdx.x * 256 + tid;
    const unsigned v = hist[i];
    s[tid] = v;
    __syncthreads();
    #pragma unroll
    for (int off = 1; off < 256; off <<= 1) {
        unsigned tv = (tid >= off) ? s[tid - off] : 0u;
        __syncthreads();
        s[tid] += tv;
        __syncthreads();
    }
    hist[i] = s[tid] - v;             // exclusive within block
    if (tid == 255) bsum[blockIdx.x] = s[255];
}

__global__ __launch_bounds__(512) void scan2_kernel(unsigned* __restrict__ bsum)
{
    __shared__ unsigned s[512];
    const int tid = threadIdx.x;
    const unsigned v = (tid < SCAN_BLOCKS) ? bsum[tid] : 0u;
    s[tid] = v;
    __syncthreads();
    #pragma unroll
    for (int off = 1; off < 512; off <<= 1) {
        unsigned tv = (tid >= off) ? s[tid - off] : 0u;
        __syncthreads();
        s[tid] += tv;
        __syncthreads();
    }
    if (tid < SCAN_BLOCKS) bsum[tid] = s[tid] - v;   // exclusive block offsets
}

__global__ __launch_bounds__(256) void scan3_kernel(unsigned* __restrict__ hist,
                                                    const unsigned* __restrict__ bsum)
{
    const int i = blockIdx.x * 256 + threadIdx.x;
    hist[i] += bsum[blockIdx.x];
}

// ---------------- Pass C: scatter point records into cell order ----------------
__global__ __launch_bounds__(256) void scatter_kernel(
    const float* __restrict__ pss, const float* __restrict__ first,
    const float* __restrict__ coef, const float* __restrict__ maxl,
    unsigned* __restrict__ cursor,
    float* __restrict__ sfx, float* __restrict__ sfy, float* __restrict__ sfz,
    unsigned* __restrict__ sbase, unsigned* __restrict__ sorig)
{
    const int t = blockIdx.x * blockDim.x + threadIdx.x;
    int b, bx, by, bz, key; float fx, fy, fz;
    point_setup(pss, first, coef, maxl, t, b, fx, fy, fz, bx, by, bz, key);
    const unsigned pos = atomicAdd(&cursor[key], 1u);
    sfx[pos] = fx;
    sfy[pos] = fy;
    sfz[pos] = fz;
    sbase[pos] = ((unsigned)b << 24) | ((unsigned)bx << 16) | ((unsigned)by << 8) | (unsigned)bz;
    sorig[pos] = (unsigned)t;
}

// ---------------- Pass D: locality-ordered gather + compute ----------------
__global__ __launch_bounds__(256) void main_kernel(
    const float* __restrict__ grid,
    const float* __restrict__ sfx, const float* __restrict__ sfy,
    const float* __restrict__ sfz, const unsigned* __restrict__ sbase,
    const unsigned* __restrict__ sorig,
    float* __restrict__ dss, float* __restrict__ nss, float* __restrict__ loss)
{
    const int i = blockIdx.x * blockDim.x + threadIdx.x;

    const float fx = sfx[i];
    const float fy = sfy[i];
    const float fz = sfz[i];
    const unsigned pk = sbase[i];
    const int b  = (int)(pk >> 24);
    const int bx = (int)((pk >> 16) & 255u);
    const int by = (int)((pk >> 8) & 255u);
    const int bz = (int)(pk & 255u);

    const float* g = grid + (size_t)b * DD * DD * DD
                          + ((size_t)bx * DD + by) * DD + bz;
    const float c000 = g[0];
    const float c001 = g[1];
    const float c010 = g[DD];
    const float c011 = g[DD + 1];
    const float c100 = g[DD * DD];
    const float c101 = g[DD * DD + 1];
    const float c110 = g[DD * DD + DD];
    const float c111 = g[DD * DD + DD + 1];

    const float wx0 = 1.0f - fx, wx1 = fx;
    const float wy0 = 1.0f - fy, wy1 = fy;
    const float wz0 = 1.0f - fz, wz1 = fz;

    const float d00 = wz0 * c000 + wz1 * c001;
    const float d01 = wz0 * c010 + wz1 * c011;
    const float d10 = wz0 * c100 + wz1 * c101;
    const float d11 = wz0 * c110 + wz1 * c111;
    const float d0  = wy0 * d00 + wy1 * d01;
    const float d1  = wy0 * d10 + wy1 * d11;
    const float dv  = wx0 * d0 + wx1 * d1;

    const float nz = wx0 * (wy0 * (c001 - c000) + wy1 * (c011 - c010))
                   + wx1 * (wy0 * (c101 - c100) + wy1 * (c111 - c110));
    const float ny = wx0 * (wz0 * (c010 - c000) + wz1 * (c011 - c001))
                   + wx1 * (wz0 * (c110 - c100) + wz1 * (c111 - c101));
    const float nx = wy0 * (wz0 * (c100 - c000) + wz1 * (c101 - c001))
                   + wy1 * (wz0 * (c110 - c010) + wz1 * (c111 - c011));

    const float nrm = sqrtf(nx * nx + ny * ny + nz * nz);
    const float inv = 1.0f / fmaxf(nrm, EPSV);

    const unsigned t = sorig[i];
    dss[t] = dv;
    float* np_ = nss + (size_t)t * 3;
    np_[0] = nx * inv;
    np_[1] = ny * inv;
    np_[2] = nz * inv;

    // loss: wave64 shuffle reduce -> LDS across 4 waves -> 1 atomic per block
    float lp = fminf(dv, 0.0f);
    #pragma unroll
    for (int off = 32; off > 0; off >>= 1)
        lp += __shfl_down(lp, off, 64);
    __shared__ float wsum[4];
    const int wid = threadIdx.x >> 6;
    if ((threadIdx.x & 63) == 0) wsum[wid] = lp;
    __syncthreads();
    if (threadIdx.x == 0)
        atomicAdd(loss, -(wsum[0] + wsum[1] + wsum[2] + wsum[3]));
}

extern "C" void kernel_launch(void* const* d_in, const int* in_sizes, int n_in,
                              void* d_out, int out_size, void* d_ws, size_t ws_size,
                              hipStream_t stream) {
    const float* pss   = (const float*)d_in[0];
    const float* grid  = (const float*)d_in[1];
    const float* first = (const float*)d_in[2];
    const float* coef  = (const float*)d_in[3];
    const float* maxl  = (const float*)d_in[4];

    float* out  = (float*)d_out;
    float* dss  = out;                          // B*N
    float* nss  = out + (size_t)BB * NN;        // B*N*3
    float* loss = out + (size_t)4 * BB * NN;    // 1

    unsigned* ws    = (unsigned*)d_ws;
    unsigned* hist  = ws;                       // TCELLS
    unsigned* bsum  = ws + TCELLS;              // 512
    float*    sfx   = (float*)(ws + SORT0 + (size_t)0 * NPTS);
    float*    sfy   = (float*)(ws + SORT0 + (size_t)1 * NPTS);
    float*    sfz   = (float*)(ws + SORT0 + (size_t)2 * NPTS);
    unsigned* sbase =          ws + SORT0 + (size_t)3 * NPTS;
    unsigned* sorig =          ws + SORT0 + (size_t)4 * NPTS;

    // zero the histogram and the loss accumulator (memset nodes are capture-safe)
    hipMemsetAsync(hist, 0, (size_t)TCELLS * sizeof(unsigned), stream);
    hipMemsetAsync(loss, 0, sizeof(float), stream);

    const int threads = 256;
    const int pblocks = NPTS / threads;         // 2048

    hist_kernel<<<pblocks, threads, 0, stream>>>(pss, first, coef, maxl, hist);
    scan1_kernel<<<SCAN_BLOCKS, 256, 0, stream>>>(hist, bsum);
    scan2_kernel<<<1, 512, 0, stream>>>(bsum);
    scan3_kernel<<<SCAN_BLOCKS, 256, 0, stream>>>(hist, bsum);
    scatter_kernel<<<pblocks, threads, 0, stream>>>(pss, first, coef, maxl, hist,
                                                    sfx, sfy, sfz, sbase, sorig);
    main_kernel<<<pblocks, threads, 0, stream>>>(grid, sfx, sfy, sfz, sbase, sorig,
                                                 dss, nss, loss);
}

// Round 3
// 375.885 us; speedup vs baseline: 1.0021x; 1.0021x over previous
//
#include <hip/hip_runtime.h>

// Problem constants (match reference)
#define BB 8
#define NN 65536
#define DD 192
#define EPSV 1e-5f

#define CAX 24                       // coarse cells per axis (192/8, cell = 8^3 voxels)
#define CELLS_B (CAX * CAX * CAX)    // 13824 cells per batch
#define TCELLS (BB * CELLS_B)        // 110592 total cells
#define NPTS (BB * NN)               // 524288 points
#define SCAN_BLOCKS (TCELLS / 256)   // 432 (exact)

// d_out layout: dss [B*N] | nss [B*N*3] | loss [1]
// d_ws layout (u32 units):
//   [0, TCELLS)                 hist / cursor
//   [TCELLS, TCELLS+512)        block sums for scan
//   RANK0  = TCELLS+512         rank[NPTS]  (u32, inverse permutation)
//   REC0   = RANK0 + NPTS       rec[NPTS]   (float4: fx,fy,fz,bits(base))
//   RES0   = REC0 + 4*NPTS      res[NPTS]   (float4: dv,nx,ny,nz — sorted order)
#define RANK0 (TCELLS + 512)
#define REC0  (RANK0 + NPTS)
#define RES0  (REC0 + 4 * NPTS)

__device__ __forceinline__ void point_setup(
    const float* __restrict__ pss, const float* __restrict__ first,
    const float* __restrict__ coef, const float* __restrict__ maxl,
    int t, int& b, float& fx, float& fy, float& fz,
    int& bx, int& by, int& bz, int& key)
{
    b = t >> 16;                      // N == 65536
    const int n = t & (NN - 1);
    const float* pb = pss + (size_t)b * 3 * NN + n;
    const float px = pb[0];
    const float py = pb[NN];
    const float pz = pb[2 * NN];

    const float Fx = fmaxf(fminf((px - first[3*b+0]) * coef[3*b+0], maxl[3*b+0]), 0.0f);
    const float Fy = fmaxf(fminf((py - first[3*b+1]) * coef[3*b+1], maxl[3*b+1]), 0.0f);
    const float Fz = fmaxf(fminf((pz - first[3*b+2]) * coef[3*b+2], maxl[3*b+2]), 0.0f);

    bx = (int)floorf(Fx);
    by = (int)floorf(Fy);
    bz = (int)floorf(Fz);
    fx = Fx - (float)bx;
    fy = Fy - (float)by;
    fz = Fz - (float)bz;

    key = ((b * CAX + (bx >> 3)) * CAX + (by >> 3)) * CAX + (bz >> 3);
}

// ---------------- Pass A: per-cell histogram ----------------
__global__ __launch_bounds__(256) void hist_kernel(
    const float* __restrict__ pss, const float* __restrict__ first,
    const float* __restrict__ coef, const float* __restrict__ maxl,
    unsigned* __restrict__ hist)
{
    const int t = blockIdx.x * blockDim.x + threadIdx.x;
    int b, bx, by, bz, key; float fx, fy, fz;
    point_setup(pss, first, coef, maxl, t, b, fx, fy, fz, bx, by, bz, key);
    atomicAdd(&hist[key], 1u);
}

// ---------------- Pass B: 3-kernel exclusive scan over TCELLS ----------------
__global__ __launch_bounds__(256) void scan1_kernel(unsigned* __restrict__ hist,
                                                    unsigned* __restrict__ bsum)
{
    __shared__ unsigned s[256];
    const int tid = threadIdx.x;
    const int i = blockIdx.x * 256 + tid;
    const unsigned v = hist[i];
    s[tid] = v;
    __syncthreads();
    #pragma unroll
    for (int off = 1; off < 256; off <<= 1) {
        unsigned tv = (tid >= off) ? s[tid - off] : 0u;
        __syncthreads();
        s[tid] += tv;
        __syncthreads();
    }
    hist[i] = s[tid] - v;             // exclusive within block
    if (tid == 255) bsum[blockIdx.x] = s[255];
}

__global__ __launch_bounds__(512) void scan2_kernel(unsigned* __restrict__ bsum)
{
    __shared__ unsigned s[512];
    const int tid = threadIdx.x;
    const unsigned v = (tid < SCAN_BLOCKS) ? bsum[tid] : 0u;
    s[tid] = v;
    __syncthreads();
    #pragma unroll
    for (int off = 1; off < 512; off <<= 1) {
        unsigned tv = (tid >= off) ? s[tid - off] : 0u;
        __syncthreads();
        s[tid] += tv;
        __syncthreads();
    }
    if (tid < SCAN_BLOCKS) bsum[tid] = s[tid] - v;   // exclusive block offsets
}

__global__ __launch_bounds__(256) void scan3_kernel(unsigned* __restrict__ hist,
                                                    const unsigned* __restrict__ bsum)
{
    const int i = blockIdx.x * 256 + threadIdx.x;
    hist[i] += bsum[blockIdx.x];
}

// ---------------- Pass C: scatter packed records; rank written coalesced ----
__global__ __launch_bounds__(256) void scatter_kernel(
    const float* __restrict__ pss, const float* __restrict__ first,
    const float* __restrict__ coef, const float* __restrict__ maxl,
    unsigned* __restrict__ cursor,
    float4* __restrict__ rec,         // sorted order, 16 B/pt
    unsigned* __restrict__ rank)      // rank[t] = sorted position (coalesced)
{
    const int t = blockIdx.x * blockDim.x + threadIdx.x;
    int b, bx, by, bz, key; float fx, fy, fz;
    point_setup(pss, first, coef, maxl, t, b, fx, fy, fz, bx, by, bz, key);
    const unsigned pos = atomicAdd(&cursor[key], 1u);
    const unsigned base = ((unsigned)b << 24) | ((unsigned)bx << 16)
                        | ((unsigned)by << 8) | (unsigned)bz;
    rec[pos] = make_float4(fx, fy, fz, __uint_as_float(base));
    rank[t] = pos;
}

// ---------------- Pass D: locality-ordered gather + compute ----------------
__global__ __launch_bounds__(256) void main_kernel(
    const float* __restrict__ grid,
    const float4* __restrict__ rec,
    float4* __restrict__ res,         // sorted order, coalesced 16 B writes
    float* __restrict__ loss)
{
    const int i = blockIdx.x * blockDim.x + threadIdx.x;

    const float4 r = rec[i];
    const float fx = r.x, fy = r.y, fz = r.z;
    const unsigned pk = __float_as_uint(r.w);
    const int b  = (int)(pk >> 24);
    const int bx = (int)((pk >> 16) & 255u);
    const int by = (int)((pk >> 8) & 255u);
    const int bz = (int)(pk & 255u);

    const float* g = grid + (size_t)b * DD * DD * DD
                          + ((size_t)bx * DD + by) * DD + bz;
    const float c000 = g[0];
    const float c001 = g[1];
    const float c010 = g[DD];
    const float c011 = g[DD + 1];
    const float c100 = g[DD * DD];
    const float c101 = g[DD * DD + 1];
    const float c110 = g[DD * DD + DD];
    const float c111 = g[DD * DD + DD + 1];

    const float wx0 = 1.0f - fx, wx1 = fx;
    const float wy0 = 1.0f - fy, wy1 = fy;
    const float wz0 = 1.0f - fz, wz1 = fz;

    const float d00 = wz0 * c000 + wz1 * c001;
    const float d01 = wz0 * c010 + wz1 * c011;
    const float d10 = wz0 * c100 + wz1 * c101;
    const float d11 = wz0 * c110 + wz1 * c111;
    const float d0  = wy0 * d00 + wy1 * d01;
    const float d1  = wy0 * d10 + wy1 * d11;
    const float dv  = wx0 * d0 + wx1 * d1;

    const float nz = wx0 * (wy0 * (c001 - c000) + wy1 * (c011 - c010))
                   + wx1 * (wy0 * (c101 - c100) + wy1 * (c111 - c110));
    const float ny = wx0 * (wz0 * (c010 - c000) + wz1 * (c011 - c001))
                   + wx1 * (wz0 * (c110 - c100) + wz1 * (c111 - c101));
    const float nx = wy0 * (wz0 * (c100 - c000) + wz1 * (c101 - c001))
                   + wy1 * (wz0 * (c110 - c010) + wz1 * (c111 - c011));

    const float nrm = sqrtf(nx * nx + ny * ny + nz * nz);
    const float inv = 1.0f / fmaxf(nrm, EPSV);

    res[i] = make_float4(dv, nx * inv, ny * inv, nz * inv);

    // loss: wave64 shuffle reduce -> LDS across 4 waves -> 1 atomic per block
    float lp = fminf(dv, 0.0f);
    #pragma unroll
    for (int off = 32; off > 0; off >>= 1)
        lp += __shfl_down(lp, off, 64);
    __shared__ float wsum[4];
    const int wid = threadIdx.x >> 6;
    if ((threadIdx.x & 63) == 0) wsum[wid] = lp;
    __syncthreads();
    if (threadIdx.x == 0)
        atomicAdd(loss, -(wsum[0] + wsum[1] + wsum[2] + wsum[3]));
}

// ---------------- Pass E: un-sort, fully coalesced output writes ------------
__global__ __launch_bounds__(256) void reorder_kernel(
    const unsigned* __restrict__ rank,
    const float4* __restrict__ res,
    float* __restrict__ dss, float* __restrict__ nss)
{
    const int t = blockIdx.x * blockDim.x + threadIdx.x;
    const float4 v = res[rank[t]];    // random 16 B read, L2/L3-resident buffer
    dss[t] = v.x;
    float* np_ = nss + (size_t)t * 3;
    np_[0] = v.y;
    np_[1] = v.z;
    np_[2] = v.w;
}

extern "C" void kernel_launch(void* const* d_in, const int* in_sizes, int n_in,
                              void* d_out, int out_size, void* d_ws, size_t ws_size,
                              hipStream_t stream) {
    const float* pss   = (const float*)d_in[0];
    const float* grid  = (const float*)d_in[1];
    const float* first = (const float*)d_in[2];
    const float* coef  = (const float*)d_in[3];
    const float* maxl  = (const float*)d_in[4];

    float* out  = (float*)d_out;
    float* dss  = out;                          // B*N
    float* nss  = out + (size_t)BB * NN;        // B*N*3
    float* loss = out + (size_t)4 * BB * NN;    // 1

    unsigned* ws   = (unsigned*)d_ws;
    unsigned* hist = ws;                        // TCELLS
    unsigned* bsum = ws + TCELLS;               // 512
    unsigned* rank = ws + RANK0;                // NPTS
    float4*   rec  = (float4*)(ws + REC0);      // NPTS float4
    float4*   res  = (float4*)(ws + RES0);      // NPTS float4

    // zero the histogram and the loss accumulator (memset nodes are capture-safe)
    hipMemsetAsync(hist, 0, (size_t)TCELLS * sizeof(unsigned), stream);
    hipMemsetAsync(loss, 0, sizeof(float), stream);

    const int threads = 256;
    const int pblocks = NPTS / threads;         // 2048

    hist_kernel<<<pblocks, threads, 0, stream>>>(pss, first, coef, maxl, hist);
    scan1_kernel<<<SCAN_BLOCKS, 256, 0, stream>>>(hist, bsum);
    scan2_kernel<<<1, 512, 0, stream>>>(bsum);
    scan3_kernel<<<SCAN_BLOCKS, 256, 0, stream>>>(hist, bsum);
    scatter_kernel<<<pblocks, threads, 0, stream>>>(pss, first, coef, maxl, hist,
                                                    rec, rank);
    main_kernel<<<pblocks, threads, 0, stream>>>(grid, rec, res, loss);
    reorder_kernel<<<pblocks, threads, 0, stream>>>(rank, res, dss, nss);
}

// Round 4
// 313.055 us; speedup vs baseline: 1.2032x; 1.2007x over previous
//
#include <hip/hip_runtime.h>

// Problem constants (match reference)
#define BB 8
#define NN 65536
#define DD 192
#define EPSV 1e-5f
#define NPTS (BB * NN)   // 524288

// d_out layout: dss [B*N] | nss [B*N*3] | loss [1]
//
// Measured conclusion (R1-R3): dur_us ~370 is dominated by fixed harness
// restore/poison traffic (~906 MB ws fill @ ~134 us + ~232 MB input restore).
// Kernel-side total is ~25-45 us; a 7-pass locality sort was net NEGATIVE
// vs this single-kernel form. Keep it minimal: 1 memset + 1 kernel.

__global__ __launch_bounds__(256) void tri_sdf_kernel(
    const float* __restrict__ pss,    // [B,3,N]
    const float* __restrict__ grid,   // [B,D,D,D]
    const float* __restrict__ first,  // [B,3]
    const float* __restrict__ coef,   // [B,3]
    const float* __restrict__ maxl,   // [B,3]
    float* __restrict__ dss,          // [B*N]
    float* __restrict__ nss,          // [B*N,3]
    float* __restrict__ loss)         // [1]
{
    // XCD batch affinity: blocks are dispatched round-robin across the 8 XCDs
    // (xcd = blockIdx % 8 heuristic). Remap so batch == (blockIdx & 7): each
    // XCD's 4 MiB L2 then caches ONE batch's 28 MB grid instead of all 8.
    // Speed-only heuristic — correctness does not depend on the mapping.
    const int vb = ((int)blockIdx.x & 7) * 256 + ((int)blockIdx.x >> 3);
    const int t  = vb * 256 + (int)threadIdx.x;     // 0 .. B*N-1
    const int b  = t >> 16;                         // N == 65536
    const int n  = t & (NN - 1);

    // --- load point (coalesced: stride-N between components) ---
    const float* pb = pss + (size_t)b * 3 * NN + n;
    const float px = pb[0];
    const float py = pb[NN];
    const float pz = pb[2 * NN];

    // --- per-batch transform params (tiny, cached/broadcast) ---
    const float fx_full = fmaxf(fminf((px - first[3*b+0]) * coef[3*b+0], maxl[3*b+0]), 0.0f);
    const float fy_full = fmaxf(fminf((py - first[3*b+1]) * coef[3*b+1], maxl[3*b+1]), 0.0f);
    const float fz_full = fmaxf(fminf((pz - first[3*b+2]) * coef[3*b+2], maxl[3*b+2]), 0.0f);

    const int bx = (int)floorf(fx_full);
    const int by = (int)floorf(fy_full);
    const int bz = (int)floorf(fz_full);
    const float fx = fx_full - (float)bx;
    const float fy = fy_full - (float)by;
    const float fz = fz_full - (float)bz;

    // --- 8-corner gather: c_{i,j,k} = grid[b][bx+i][by+j][bz+k] ---
    const float* g = grid + (size_t)b * DD * DD * DD
                          + ((size_t)bx * DD + by) * DD + bz;
    const float c000 = g[0];
    const float c001 = g[1];
    const float c010 = g[DD];
    const float c011 = g[DD + 1];
    const float c100 = g[DD * DD];
    const float c101 = g[DD * DD + 1];
    const float c110 = g[DD * DD + DD];
    const float c111 = g[DD * DD + DD + 1];

    const float wx0 = 1.0f - fx, wx1 = fx;
    const float wy0 = 1.0f - fy, wy1 = fy;
    const float wz0 = 1.0f - fz, wz1 = fz;

    // trilinear value
    const float d00 = wz0 * c000 + wz1 * c001;
    const float d01 = wz0 * c010 + wz1 * c011;
    const float d10 = wz0 * c100 + wz1 * c101;
    const float d11 = wz0 * c110 + wz1 * c111;
    const float d0  = wy0 * d00 + wy1 * d01;
    const float d1  = wy0 * d10 + wy1 * d11;
    const float dv  = wx0 * d0 + wx1 * d1;

    // finite-difference normals (match reference einsums exactly)
    const float nz = wx0 * (wy0 * (c001 - c000) + wy1 * (c011 - c010))
                   + wx1 * (wy0 * (c101 - c100) + wy1 * (c111 - c110));
    const float ny = wx0 * (wz0 * (c010 - c000) + wz1 * (c011 - c001))
                   + wx1 * (wz0 * (c110 - c100) + wz1 * (c111 - c101));
    const float nx = wy0 * (wz0 * (c100 - c000) + wz1 * (c101 - c001))
                   + wy1 * (wz0 * (c110 - c010) + wz1 * (c111 - c011));

    const float nrm = sqrtf(nx * nx + ny * ny + nz * nz);
    const float inv = 1.0f / fmaxf(nrm, EPSV);

    // --- stores ---
    dss[t] = dv;
    float* np_ = nss + (size_t)t * 3;
    np_[0] = nx * inv;
    np_[1] = ny * inv;
    np_[2] = nz * inv;

    // --- loss: wave64 shuffle reduce -> LDS -> 1 atomic per block ---
    float lp = fminf(dv, 0.0f);
    #pragma unroll
    for (int off = 32; off > 0; off >>= 1)
        lp += __shfl_down(lp, off, 64);
    __shared__ float wsum[4];
    const int wid = threadIdx.x >> 6;
    if ((threadIdx.x & 63) == 0) wsum[wid] = lp;
    __syncthreads();
    if (threadIdx.x == 0)
        atomicAdd(loss, -(wsum[0] + wsum[1] + wsum[2] + wsum[3]));
}

extern "C" void kernel_launch(void* const* d_in, const int* in_sizes, int n_in,
                              void* d_out, int out_size, void* d_ws, size_t ws_size,
                              hipStream_t stream) {
    const float* pss   = (const float*)d_in[0];
    const float* grid  = (const float*)d_in[1];
    const float* first = (const float*)d_in[2];
    const float* coef  = (const float*)d_in[3];
    const float* maxl  = (const float*)d_in[4];

    float* out  = (float*)d_out;
    float* dss  = out;                          // B*N
    float* nss  = out + (size_t)BB * NN;        // B*N*3
    float* loss = out + (size_t)4 * BB * NN;    // 1

    // harness poisons d_out with 0xAA before each timed replay — zero the
    // loss accumulator (memset node is graph-capture safe)
    hipMemsetAsync(loss, 0, sizeof(float), stream);

    const int threads = 256;
    const int blocks  = NPTS / threads;         // 2048
    tri_sdf_kernel<<<blocks, threads, 0, stream>>>(pss, grid, first, coef, maxl,
                                                   dss, nss, loss);
}

// Round 5
// 310.329 us; speedup vs baseline: 1.2138x; 1.0088x over previous
//
#include <hip/hip_runtime.h>

// Problem constants (match reference)
#define BB 8
#define NN 65536
#define DD 192
#define EPSV 1e-5f
#define NPTS (BB * NN)       // 524288
#define NBLK 1024            // main-kernel blocks (2 points/thread)

// d_out layout: dss [B*N] | nss [B*N*3] | loss [1]
// d_ws: partial[NBLK] floats (block partial sums of min(dss,0))
//
// Journal (R1-R4): dur_us carries ~210+ us fixed harness restore/poison tax.
// R4's -55 us came from (a) killing 3/4 of same-address loss atomics
// (8192->2048 serialize at one TCC line, ~35 cyc each -> ~40 us drain) and
// (b) XCD batch-affinity swizzle (batch == blockIdx&7 -> each XCD L2 caches
// one 28 MB grid, ~14% resident). R5: no global atomics at all (block
// partials + tiny reduce kernel) and 2 pts/thread for 2x gather MLP.

__global__ __launch_bounds__(256) void tri_sdf_kernel(
    const float* __restrict__ pss,     // [B,3,N]
    const float* __restrict__ grid,    // [B,D,D,D]
    const float* __restrict__ first,   // [B,3]
    const float* __restrict__ coef,    // [B,3]
    const float* __restrict__ maxl,    // [B,3]
    float* __restrict__ dss,           // [B*N]
    float* __restrict__ nss,           // [B*N,3]
    float* __restrict__ partial)       // [NBLK]
{
    // XCD batch affinity: batch == blockIdx & 7 (round-robin block->XCD).
    // Each block covers 512 consecutive points of one batch.
    const int vb = ((int)blockIdx.x & 7) * 128 + ((int)blockIdx.x >> 3);
    const int t0 = vb * 512 + (int)threadIdx.x;     // point A; point B = t0+256
    const int b  = t0 >> 16;
    const int n0 = t0 & (NN - 1);

    // --- coalesced point loads for both points ---
    const float* pb = pss + (size_t)b * 3 * NN + n0;
    const float pxA = pb[0],        pxB = pb[256];
    const float pyA = pb[NN],       pyB = pb[NN + 256];
    const float pzA = pb[2 * NN],   pzB = pb[2 * NN + 256];

    const float f0x = first[3*b+0], f0y = first[3*b+1], f0z = first[3*b+2];
    const float cfx = coef[3*b+0],  cfy = coef[3*b+1],  cfz = coef[3*b+2];
    const float mlx = maxl[3*b+0],  mly = maxl[3*b+1],  mlz = maxl[3*b+2];

    const float FxA = fmaxf(fminf((pxA - f0x) * cfx, mlx), 0.0f);
    const float FyA = fmaxf(fminf((pyA - f0y) * cfy, mly), 0.0f);
    const float FzA = fmaxf(fminf((pzA - f0z) * cfz, mlz), 0.0f);
    const float FxB = fmaxf(fminf((pxB - f0x) * cfx, mlx), 0.0f);
    const float FyB = fmaxf(fminf((pyB - f0y) * cfy, mly), 0.0f);
    const float FzB = fmaxf(fminf((pzB - f0z) * cfz, mlz), 0.0f);

    const int bxA = (int)floorf(FxA), byA = (int)floorf(FyA), bzA = (int)floorf(FzA);
    const int bxB = (int)floorf(FxB), byB = (int)floorf(FyB), bzB = (int)floorf(FzB);
    const float fxA = FxA - (float)bxA, fyA = FyA - (float)byA, fzA = FzA - (float)bzA;
    const float fxB = FxB - (float)bxB, fyB = FyB - (float)byB, fzB = FzB - (float)bzB;

    // --- issue all 16 corner loads before any use (2x MLP) ---
    const float* gbase = grid + (size_t)b * DD * DD * DD;
    const float* gA = gbase + ((size_t)bxA * DD + byA) * DD + bzA;
    const float* gB = gbase + ((size_t)bxB * DD + byB) * DD + bzB;

    const float a000 = gA[0];
    const float a001 = gA[1];
    const float a010 = gA[DD];
    const float a011 = gA[DD + 1];
    const float a100 = gA[DD * DD];
    const float a101 = gA[DD * DD + 1];
    const float a110 = gA[DD * DD + DD];
    const float a111 = gA[DD * DD + DD + 1];
    const float b000 = gB[0];
    const float b001 = gB[1];
    const float b010 = gB[DD];
    const float b011 = gB[DD + 1];
    const float b100 = gB[DD * DD];
    const float b101 = gB[DD * DD + 1];
    const float b110 = gB[DD * DD + DD];
    const float b111 = gB[DD * DD + DD + 1];

    // ---------- point A ----------
    float wx0 = 1.0f - fxA, wx1 = fxA;
    float wy0 = 1.0f - fyA, wy1 = fyA;
    float wz0 = 1.0f - fzA, wz1 = fzA;

    float d00 = wz0 * a000 + wz1 * a001;
    float d01 = wz0 * a010 + wz1 * a011;
    float d10 = wz0 * a100 + wz1 * a101;
    float d11 = wz0 * a110 + wz1 * a111;
    const float dvA = wx0 * (wy0 * d00 + wy1 * d01) + wx1 * (wy0 * d10 + wy1 * d11);

    const float nzA = wx0 * (wy0 * (a001 - a000) + wy1 * (a011 - a010))
                    + wx1 * (wy0 * (a101 - a100) + wy1 * (a111 - a110));
    const float nyA = wx0 * (wz0 * (a010 - a000) + wz1 * (a011 - a001))
                    + wx1 * (wz0 * (a110 - a100) + wz1 * (a111 - a101));
    const float nxA = wy0 * (wz0 * (a100 - a000) + wz1 * (a101 - a001))
                    + wy1 * (wz0 * (a110 - a010) + wz1 * (a111 - a011));
    const float invA = 1.0f / fmaxf(sqrtf(nxA*nxA + nyA*nyA + nzA*nzA), EPSV);

    // ---------- point B ----------
    wx0 = 1.0f - fxB; wx1 = fxB;
    wy0 = 1.0f - fyB; wy1 = fyB;
    wz0 = 1.0f - fzB; wz1 = fzB;

    d00 = wz0 * b000 + wz1 * b001;
    d01 = wz0 * b010 + wz1 * b011;
    d10 = wz0 * b100 + wz1 * b101;
    d11 = wz0 * b110 + wz1 * b111;
    const float dvB = wx0 * (wy0 * d00 + wy1 * d01) + wx1 * (wy0 * d10 + wy1 * d11);

    const float nzB = wx0 * (wy0 * (b001 - b000) + wy1 * (b011 - b010))
                    + wx1 * (wy0 * (b101 - b100) + wy1 * (b111 - b110));
    const float nyB = wx0 * (wz0 * (b010 - b000) + wz1 * (b011 - b001))
                    + wx1 * (wz0 * (b110 - b100) + wz1 * (b111 - b101));
    const float nxB = wy0 * (wz0 * (b100 - b000) + wz1 * (b101 - b001))
                    + wy1 * (wz0 * (b110 - b010) + wz1 * (b111 - b011));
    const float invB = 1.0f / fmaxf(sqrtf(nxB*nxB + nyB*nyB + nzB*nzB), EPSV);

    // --- stores ---
    dss[t0]       = dvA;
    dss[t0 + 256] = dvB;
    float* npA = nss + (size_t)t0 * 3;
    npA[0] = nxA * invA;
    npA[1] = nyA * invA;
    npA[2] = nzA * invA;
    float* npB = nss + (size_t)(t0 + 256) * 3;
    npB[0] = nxB * invB;
    npB[1] = nyB * invB;
    npB[2] = nzB * invB;

    // --- block partial of sum(min(dss,0)): shuffle -> LDS -> plain store ---
    float lp = fminf(dvA, 0.0f) + fminf(dvB, 0.0f);
    #pragma unroll
    for (int off = 32; off > 0; off >>= 1)
        lp += __shfl_down(lp, off, 64);
    __shared__ float wsum[4];
    const int wid = threadIdx.x >> 6;
    if ((threadIdx.x & 63) == 0) wsum[wid] = lp;
    __syncthreads();
    if (threadIdx.x == 0)
        partial[blockIdx.x] = wsum[0] + wsum[1] + wsum[2] + wsum[3];
}

// 1024 partials -> loss = -sum  (single block, no atomics anywhere)
__global__ __launch_bounds__(256) void loss_reduce_kernel(
    const float* __restrict__ partial, float* __restrict__ loss)
{
    const int tid = threadIdx.x;
    float s = partial[tid] + partial[tid + 256]
            + partial[tid + 512] + partial[tid + 768];
    #pragma unroll
    for (int off = 32; off > 0; off >>= 1)
        s += __shfl_down(s, off, 64);
    __shared__ float wsum[4];
    const int wid = tid >> 6;
    if ((tid & 63) == 0) wsum[wid] = s;
    __syncthreads();
    if (tid == 0)
        loss[0] = -(wsum[0] + wsum[1] + wsum[2] + wsum[3]);
}

extern "C" void kernel_launch(void* const* d_in, const int* in_sizes, int n_in,
                              void* d_out, int out_size, void* d_ws, size_t ws_size,
                              hipStream_t stream) {
    const float* pss   = (const float*)d_in[0];
    const float* grid  = (const float*)d_in[1];
    const float* first = (const float*)d_in[2];
    const float* coef  = (const float*)d_in[3];
    const float* maxl  = (const float*)d_in[4];

    float* out  = (float*)d_out;
    float* dss  = out;                          // B*N
    float* nss  = out + (size_t)BB * NN;        // B*N*3
    float* loss = out + (size_t)4 * BB * NN;    // 1

    float* partial = (float*)d_ws;              // NBLK floats

    tri_sdf_kernel<<<NBLK, 256, 0, stream>>>(pss, grid, first, coef, maxl,
                                             dss, nss, partial);
    loss_reduce_kernel<<<1, 256, 0, stream>>>(partial, loss);
}